// Round 7
// baseline (376.011 us; speedup 1.0000x reference)
//
#include <hip/hip_runtime.h>
#include <math.h>

#define BATCH 2048
#define LDIM 64
#define EDIM 256
#define UDIM 512
#define G 8
#define NBLK (BATCH / G)   // 256 blocks = 1 per CU

typedef __attribute__((ext_vector_type(8))) _Float16 half8;
typedef __attribute__((ext_vector_type(4))) float floatx4;

__device__ inline float tanh_fast(float x) {
    float t = __builtin_amdgcn_exp2f(x * 2.88539008177792681f);
    return 1.f - 2.f * __builtin_amdgcn_rcpf(t + 1.f);
}
__device__ inline half8 cvt8(float4 f0, float4 f1) {
    half8 h;
    h[0] = (_Float16)f0.x; h[1] = (_Float16)f0.y;
    h[2] = (_Float16)f0.z; h[3] = (_Float16)f0.w;
    h[4] = (_Float16)f1.x; h[5] = (_Float16)f1.y;
    h[6] = (_Float16)f1.z; h[7] = (_Float16)f1.w;
    return h;
}
// B-fragment pointer: layout [kc][ntg(32)][lane(64)][8 fp16]
__device__ inline const half8* bfrag(const unsigned short* F, int kc, int ntg, int l) {
    return (const half8*)(F + ((((size_t)kc * 32 + ntg) * 64 + l) << 3));
}
// LDS barrier WITHOUT vmcnt drain: keeps prefetch loads in flight.
#define LGKM_BARRIER() asm volatile("s_waitcnt lgkmcnt(0)\ns_barrier" ::: "memory")

// ---- prep: W[K][512] fp32 -> fp16 B-fragments via coalesced LDS slab. ----
__global__ __launch_bounds__(256) void prep_frag(const float* __restrict__ W1,
                                                 const float* __restrict__ W2,
                                                 unsigned short* __restrict__ F1,
                                                 unsigned short* __restrict__ F2) {
    __shared__ float S[32 * 128];
    int bid = blockIdx.x;
    const float* W; unsigned short* F; int kc, grp;
    if (bid < 32) { W = W1; F = F1; kc = bid >> 2; grp = bid & 3; }
    else { bid -= 32; W = W2; F = F2; kc = bid >> 2; grp = bid & 3; }
    const int tid = threadIdx.x;
    const float* src = W + (size_t)kc * 32 * UDIM + grp * 128;
    float4* Sv = (float4*)S;
#pragma unroll
    for (int i = 0; i < 4; ++i) {
        int f = tid + i * 256;
        int k = f >> 5, c4 = f & 31;
        Sv[f] = *(const float4*)(src + (size_t)k * UDIM + c4 * 4);
    }
    __syncthreads();
#pragma unroll
    for (int i = 0; i < 2; ++i) {
        int u = tid + i * 256;
        int lane = u & 63, ntl = u >> 6;
        int n_loc = ntl * 16 + (lane & 15);
        int k0 = (lane >> 4) * 8;
        half8 h;
#pragma unroll
        for (int j = 0; j < 8; ++j)
            h[j] = (_Float16)S[(k0 + j) * 128 + n_loc];
        int ntg = grp * 8 + ntl;
        *(half8*)(F + (((size_t)kc * 32 + ntg) * 64 + lane) * 8) = h;
    }
}

// ---- main: persistent, 1 block/CU, G batches. A fp16 double-buffer in LDS,
// XOR-swizzled octets; 2-chunk transient staging; lgkm-only mid barriers. ----
__global__ __launch_bounds__(1024, 4) void attn_main(
    const float* __restrict__ feat, const unsigned short* __restrict__ F1,
    const unsigned short* __restrict__ F2, const float* __restrict__ hidden,
    const float* __restrict__ b1, const float* __restrict__ b2,
    const float* __restrict__ Vw, const float* __restrict__ bv,
    float* __restrict__ ctx_out, float* __restrict__ w_out)
{
    extern __shared__ char smem[];
    _Float16* lA0  = (_Float16*)smem;              // 32 KB  [slot(2048)][8]
    _Float16* lA1  = lA0 + 16384;                  // 32 KB
    float* ph_all  = (float*)(smem + 65536);       // [8][512]  16 KB
    float* hl      = ph_all + 8 * 512;             // [8][516]  16.1 KB
    float* Vl      = hl + 8 * 516;                 // 512 f
    float* scp     = Vl + 512;                     // [16][32]
    float* ctxp    = scp + 16 * 32;                // [16][256] 16 KB
    float* wsm     = ctxp + 16 * 256;              // 64 f   (total 119168 B)

    const int tid = threadIdx.x;
    const int w = tid >> 6, l = tid & 63;
    const int mg = w & 1, ng = w >> 1;   // wave tile: 32 rows x 64 cols
    const size_t b0 = (size_t)blockIdx.x * G;
    const float* fbase = feat + b0 * (LDIM * EDIM);

    // ---- prologue: hidden + V staged ----
    *(float4*)&hl[(tid >> 7) * 516 + (tid & 127) * 4] =
        *(const float4*)(hidden + b0 * UDIM + tid * 4);
    if (tid < 512) Vl[tid] = Vw[tid];
    __syncthreads();

    // issue A(0) staging loads (both chunks; ph compute covers them)
    const int s0 = tid, r0s = s0 >> 5, o0s = (s0 & 31) ^ (r0s & 7);
    const int s1 = 1024 + tid, r1s = s1 >> 5, o1s = (s1 & 31) ^ (r1s & 7);
    float4 c0a, c0b, c1a, c1b;
    {
        const float* p = fbase + r0s * EDIM + o0s * 8;
        c0a = ((const float4*)p)[0]; c0b = ((const float4*)p)[1];
        const float* q = fbase + r1s * EDIM + o1s * 8;
        c1a = ((const float4*)q)[0]; c1b = ((const float4*)q)[1];
    }

    // ph = hidden @ W2 + b1 + b2 (M=16 pad, rows l&7 duplicated)
    {
        floatx4 pacc[2];
        pacc[0] = (floatx4){0.f, 0.f, 0.f, 0.f};
        pacc[1] = (floatx4){0.f, 0.f, 0.f, 0.f};
        const float* hrow = hl + (l & 7) * 516 + ((l >> 4) << 3);
#pragma unroll 2
        for (int kc = 0; kc < 16; ++kc) {
            float4 h0 = *(const float4*)(hrow + kc * 32);
            float4 h1 = *(const float4*)(hrow + kc * 32 + 4);
            half8 a = cvt8(h0, h1);
#pragma unroll
            for (int nt = 0; nt < 2; ++nt) {
                half8 bf = *bfrag(F2, kc, w * 2 + nt, l);
                pacc[nt] = __builtin_amdgcn_mfma_f32_16x16x32_f16(a, bf, pacc[nt], 0, 0, 0);
            }
        }
#pragma unroll
        for (int nt = 0; nt < 2; ++nt) {
            const int n = (w * 2 + nt) * 16 + (l & 15);
            const float bias = b1[n] + b2[n];
            if ((l >> 4) < 2) {
#pragma unroll
                for (int r = 0; r < 4; ++r)
                    ph_all[((l >> 4) * 4 + r) * UDIM + n] = pacc[nt][r] + bias;
            }
        }
    }
    // store A(0)
    *(half8*)(lA0 + s0 * 8) = cvt8(c0a, c0b);
    *(half8*)(lA0 + s1 * 8) = cvt8(c1a, c1b);
    __syncthreads();

    const float bvv = bv[0];

    for (int g = 0; g < G; ++g) {
        _Float16* bufc = (g & 1) ? lA1 : lA0;
        _Float16* bufn = (g & 1) ? lA0 : lA1;
        const float* fbn = fbase + (size_t)(g + 1) * (LDIM * EDIM);

        // chunk0 issue (next batch; in flight across GEMM)
        float4 k0a, k0b;
        if (g < G - 1) {
            const float* p = fbn + r0s * EDIM + o0s * 8;
            k0a = ((const float4*)p)[0]; k0b = ((const float4*)p)[1];
        }

        // ---- GEMM: wave = 32 rows (mg) x 64 cols (ng), 8 kc, no barriers ----
        floatx4 acc[4][2];  // [nt][mt]
#pragma unroll
        for (int i = 0; i < 4; ++i)
#pragma unroll
            for (int j = 0; j < 2; ++j) acc[i][j] = (floatx4){0.f, 0.f, 0.f, 0.f};
#pragma unroll
        for (int kc = 0; kc < 8; ++kc) {
            half8 a[2], B[4];
#pragma unroll
            for (int mt = 0; mt < 2; ++mt) {
                const int row = mg * 32 + mt * 16 + (l & 15);
                const int phys = (kc * 4 + (l >> 4)) ^ (row & 7);
                a[mt] = *(const half8*)(bufc + row * 256 + phys * 8);
            }
#pragma unroll
            for (int nt = 0; nt < 4; ++nt) B[nt] = *bfrag(F1, kc, ng * 4 + nt, l);
#pragma unroll
            for (int nt = 0; nt < 4; ++nt)
#pragma unroll
                for (int mt = 0; mt < 2; ++mt)
                    acc[nt][mt] = __builtin_amdgcn_mfma_f32_16x16x32_f16(
                        a[mt], B[nt], acc[nt][mt], 0, 0, 0);
        }

        // chunk0 store, chunk1 issue
        float4 k1a, k1b;
        if (g < G - 1) {
            *(half8*)(bufn + s0 * 8) = cvt8(k0a, k0b);
            const float* p = fbn + r1s * EDIM + o1s * 8;
            k1a = ((const float4*)p)[0]; k1b = ((const float4*)p)[1];
        }

        // ---- epilogue: tanh(acc + ph) * V -> per-row score partials ----
        float sv[2][4];
#pragma unroll
        for (int mt = 0; mt < 2; ++mt)
#pragma unroll
            for (int r = 0; r < 4; ++r) sv[mt][r] = 0.f;
#pragma unroll
        for (int nt = 0; nt < 4; ++nt) {
            const int n = (ng * 4 + nt) * 16 + (l & 15);
            const float phn = ph_all[g * UDIM + n];
            const float vn  = Vl[n];
#pragma unroll
            for (int mt = 0; mt < 2; ++mt)
#pragma unroll
                for (int r = 0; r < 4; ++r)
                    sv[mt][r] += tanh_fast(acc[nt][mt][r] + phn) * vn;
        }
#pragma unroll
        for (int mt = 0; mt < 2; ++mt)
#pragma unroll
            for (int r = 0; r < 4; ++r) {
                float v = sv[mt][r];
                v += __shfl_xor(v, 1);
                v += __shfl_xor(v, 2);
                v += __shfl_xor(v, 4);
                v += __shfl_xor(v, 8);
                if ((l & 15) == 0) scp[w * 32 + mt * 16 + (l >> 4) * 4 + r] = v;
            }
        LGKM_BARRIER();

        // ---- softmax over L=64 ----
        if (tid < 64) {
            float s = bvv;
#pragma unroll
            for (int k = 0; k < 8; ++k)
                s += scp[(2 * k + (tid >> 5)) * 32 + (tid & 31)];
            float m = s;
            m = fmaxf(m, __shfl_xor(m, 32));
            m = fmaxf(m, __shfl_xor(m, 16));
            m = fmaxf(m, __shfl_xor(m, 8));
            m = fmaxf(m, __shfl_xor(m, 4));
            m = fmaxf(m, __shfl_xor(m, 2));
            m = fmaxf(m, __shfl_xor(m, 1));
            float e = __builtin_amdgcn_exp2f((s - m) * 1.44269504088896341f);
            float sum = e;
            sum += __shfl_xor(sum, 32);
            sum += __shfl_xor(sum, 16);
            sum += __shfl_xor(sum, 8);
            sum += __shfl_xor(sum, 4);
            sum += __shfl_xor(sum, 2);
            sum += __shfl_xor(sum, 1);
            float wgt = e / sum;
            wsm[tid] = wgt;
            w_out[(b0 + g) * LDIM + tid] = wgt;
        }
        LGKM_BARRIER();

        // ---- ctx partials from LDS (fp16 A), swizzled reads ----
        {
            const int oe = tid & 31, rr = tid >> 5;  // rows rr, rr+32
            float p8[8];
#pragma unroll
            for (int j = 0; j < 8; ++j) p8[j] = 0.f;
#pragma unroll
            for (int h = 0; h < 2; ++h) {
                const int row = rr + h * 32;
                const int phys = oe ^ (row & 7);
                half8 v = *(const half8*)(bufc + row * 256 + phys * 8);
                const float wr = wsm[row];
#pragma unroll
                for (int j = 0; j < 8; ++j) p8[j] = fmaf(wr, (float)v[j], p8[j]);
            }
#pragma unroll
            for (int j = 0; j < 8; ++j) p8[j] += __shfl_xor(p8[j], 32);
            if (l < 32) {
                *(float4*)&ctxp[w * 256 + l * 8] =
                    float4{p8[0], p8[1], p8[2], p8[3]};
                *(float4*)&ctxp[w * 256 + l * 8 + 4] =
                    float4{p8[4], p8[5], p8[6], p8[7]};
            }
        }
        // chunk1 store
        if (g < G - 1) *(half8*)(bufn + s1 * 8) = cvt8(k1a, k1b);
        LGKM_BARRIER();

        if (tid < 256) {
            float c = 0.f;
#pragma unroll
            for (int k = 0; k < 16; ++k) c += ctxp[k * 256 + tid];
            ctx_out[(b0 + g) * EDIM + tid] = c;
        }
        __syncthreads();  // full drain: bufn ready, scp/wsm reusable
    }
}

extern "C" void kernel_launch(void* const* d_in, const int* in_sizes, int n_in,
                              void* d_out, int out_size, void* d_ws, size_t ws_size,
                              hipStream_t stream) {
    const float* features = (const float*)d_in[0];
    const float* hidden   = (const float*)d_in[1];
    const float* W1       = (const float*)d_in[2];
    const float* b1       = (const float*)d_in[3];
    const float* W2       = (const float*)d_in[4];
    const float* b2       = (const float*)d_in[5];
    const float* Vw       = (const float*)d_in[6];
    const float* bv       = (const float*)d_in[7];

    float* ctx_out = (float*)d_out;
    float* w_out   = (float*)d_out + (size_t)BATCH * EDIM;

    unsigned short* F1 = (unsigned short*)d_ws;            // 256 KB
    unsigned short* F2 = F1 + (size_t)8 * 32 * 64 * 8;     // 512 KB

    prep_frag<<<dim3(96), dim3(256), 0, stream>>>(W1, W2, F1, F2);

    const int smem = 119168;
    hipFuncSetAttribute((const void*)attn_main,
                        hipFuncAttributeMaxDynamicSharedMemorySize, 131072);
    attn_main<<<dim3(NBLK), dim3(1024), smem, stream>>>(
        features, F1, F2, hidden, b1, b2, Vw, bv, ctx_out, w_out);
}